// Round 8
// baseline (1694.503 us; speedup 1.0000x reference)
//
#include <hip/hip_runtime.h>
#include <hip/hip_bf16.h>
#include <cstdint>
#include <cstddef>

#define PI_F 3.14159265358979323846f
#define TWO_PI_F 6.28318530717958647692f

typedef __bf16 bf16x8 __attribute__((ext_vector_type(8)));
typedef __bf16 bf16x4 __attribute__((ext_vector_type(4)));
typedef float  f32x4  __attribute__((ext_vector_type(4)));

__device__ __forceinline__ __bf16 to_bf16(float f) { return (__bf16)f; }

// global -> LDS async copy, 16B per lane; LDS dest = wave-uniform base + lane*16
#define GLD_LDS16(gsrc, ldst)                                            \
  __builtin_amdgcn_global_load_lds(                                      \
      (const __attribute__((address_space(1))) void*)(gsrc),             \
      (__attribute__((address_space(3))) void*)(ldst), 16, 0, 0)

// ---------------------------------------------------------------------------
// Build machinery (inline-trig variant; params table kernel eliminated).
// ---------------------------------------------------------------------------
struct P8 {
  float4 qa[8];
  float4 qb[8];
  float4 cc[8];
};

__device__ __forceinline__ void loadP8(P8& P, int lb, int lane,
    const float* __restrict__ theta, const float* __restrict__ phi) {
#pragma unroll
  for (int k = 0; k < 8; ++k) {
    int idx = (lb + k) * 128 + 2 * lane;
    float2 th = *(const float2*)&theta[idx];
    float2 ph = *(const float2*)&phi[idx];
    float ta = fmodf(th.x, PI_F), pa = ph.x;
    if (ta > 0.5f * PI_F) { ta = PI_F - ta; pa += PI_F; }
    pa = fmodf(pa, TWO_PI_F);
    float tb = fmodf(th.y, PI_F), pb = ph.y;
    if (tb > 0.5f * PI_F) { tb = PI_F - tb; pb += PI_F; }
    pb = fmodf(pb, TWO_PI_F);
    float ca = cosf(ta), sa = sinf(ta), cpa = cosf(pa), spa = sinf(pa);
    float cb = cosf(tb), sb = sinf(tb), cpb = cosf(pb), spb = sinf(pb);
    P.qa[k] = make_float4(cpa * ca, spa * ca, cpa * sa, spa * sa);
    P.qb[k] = make_float4(cpb * cb, spb * cb, cpb * sb, spb * sb);
    P.cc[k] = make_float4(ca, sa, cb, sb);
  }
}

__device__ __forceinline__ void layer_step(bool odd, int lane,
    float4 qa, float4 qb, float4 cc,
    float& vre0, float& vim0, float& vre1, float& vim1,
    float& vre2, float& vim2, float& vre3, float& vim3) {
  if (!odd) {
    float nr0 = qa.x * vre0 - qa.y * vim0 + qa.z * vre1 - qa.w * vim1;
    float ni0 = qa.x * vim0 + qa.y * vre0 + qa.z * vim1 + qa.w * vre1;
    float nr1 = cc.x * vre1 - cc.y * vre0;
    float ni1 = cc.x * vim1 - cc.y * vim0;
    float nr2 = qb.x * vre2 - qb.y * vim2 + qb.z * vre3 - qb.w * vim3;
    float ni2 = qb.x * vim2 + qb.y * vre2 + qb.z * vim3 + qb.w * vre3;
    float nr3 = cc.z * vre3 - cc.w * vre2;
    float ni3 = cc.z * vim3 - cc.w * vim2;
    vre0 = nr0; vim0 = ni0; vre1 = nr1; vim1 = ni1;
    vre2 = nr2; vim2 = ni2; vre3 = nr3; vim3 = ni3;
  } else {
    int nxt = (lane + 1) & 63, prv = (lane + 63) & 63;
    float xre = __shfl(vre0, nxt, 64);
    float xim = __shfl(vim0, nxt, 64);
    float pre = __shfl(vre3, prv, 64);
    float pim = __shfl(vim3, prv, 64);
    float cp  = __shfl(cc.z, prv, 64);
    float sp  = __shfl(cc.w, prv, 64);
    float nr1 = qa.x * vre1 - qa.y * vim1 + qa.z * vre2 - qa.w * vim2;
    float ni1 = qa.x * vim1 + qa.y * vre1 + qa.z * vim2 + qa.w * vre2;
    float nr2 = cc.x * vre2 - cc.y * vre1;
    float ni2 = cc.x * vim2 - cc.y * vim1;
    float nr3 = qb.x * vre3 - qb.y * vim3 + qb.z * xre - qb.w * xim;
    float ni3 = qb.x * vim3 + qb.y * vre3 + qb.z * xim + qb.w * xre;
    float nr0 = cp * vre0 - sp * pre;
    float ni0 = cp * vim0 - sp * pim;
    vre0 = nr0; vim0 = ni0; vre1 = nr1; vim1 = ni1;
    vre2 = nr2; vim2 = ni2; vre3 = nr3; vim3 = ni3;
  }
}

// ---------------------------------------------------------------------------
// FUSED kernel. Grid = 768 blocks x 256 thr = exactly 3 blocks/CU — provably
// all-resident (VGPR cap 170 x 12 waves, LDS 3x32KB=96 <= 160KB), so the
// flag spin cannot deadlock regardless of dispatch order.
//   blocks 0..15 : build T (4 rows each) -> Tb2 (frag-ordered), release++flag
//   blocks 16+   : issue nt-prefetch of their first 2 x-tiles, spin on flag
//   all          : stage B (32KB) -> LDS, then free-running MFMA tile loop,
//                  nt loads/stores (x/out touched exactly once -> no L3 alloc)
// ---------------------------------------------------------------------------
__global__ __launch_bounds__(256, 3) void olk_fused(
    const float* __restrict__ x, const float* __restrict__ theta,
    const float* __restrict__ phi, const float* __restrict__ outph,
    float* __restrict__ out, unsigned* __restrict__ flag,
    __bf16* __restrict__ Tb2) {
  __shared__ __bf16 Bl[32 * 512];   // 32 frag-sets x 64 lanes x 8 bf16 = 32KB
  int tid = threadIdx.x, lane = tid & 63, w = tid >> 6;
  int l15 = lane & 15, lg = lane >> 4;
  int bid = blockIdx.x;
  int g = bid * 4 + w;              // global wave id 0..3071

  // ---- tile chunk assignment (8192 tiles over 3072 waves) ----
  int start, cnt;
  if (g < 64)        { start = g * 2;               cnt = 2; }   // build waves
  else if (g < 2112) { start = 128 + (g - 64) * 3;  cnt = 3; }
  else               { start = 6272 + (g - 2112) * 2; cnt = 2; }

  f32x4 La[16], Lb[16];
  bf16x8 a[8];
  f32x4 acc[4];

#define ISSUE(arr, t)                                                     \
  do {                                                                    \
    const float* xr_ = x + ((size_t)((t) * 16 + l15) << 8) + 4 * lg;      \
    __builtin_amdgcn_sched_barrier(0);                                    \
    _Pragma("unroll")                                                     \
    for (int ks = 0; ks < 8; ++ks) {                                      \
      arr[2 * ks]     = __builtin_nontemporal_load((const f32x4*)(xr_ + ks * 32));      \
      arr[2 * ks + 1] = __builtin_nontemporal_load((const f32x4*)(xr_ + ks * 32 + 16)); \
    }                                                                     \
    __builtin_amdgcn_sched_barrier(0);                                    \
  } while (0)

#define CVT(arr)                                                          \
  do {                                                                    \
    _Pragma("unroll")                                                     \
    for (int ks = 0; ks < 8; ++ks) {                                      \
      f32x4 lo_ = arr[2 * ks], hi_ = arr[2 * ks + 1];                     \
      bf16x8 v_;                                                          \
      v_[0] = to_bf16(lo_.x); v_[1] = to_bf16(lo_.y);                     \
      v_[2] = to_bf16(lo_.z); v_[3] = to_bf16(lo_.w);                     \
      v_[4] = to_bf16(hi_.x); v_[5] = to_bf16(hi_.y);                     \
      v_[6] = to_bf16(hi_.z); v_[7] = to_bf16(hi_.w);                     \
      a[ks] = v_;                                                         \
    }                                                                     \
  } while (0)

#define MFMA(bb)                                                          \
  do {                                                                    \
    _Pragma("unroll")                                                     \
    for (int nt = 0; nt < 4; ++nt) acc[nt] = (f32x4){0.f, 0.f, 0.f, 0.f}; \
    _Pragma("unroll")                                                     \
    for (int ks = 0; ks < 8; ++ks)                                        \
      _Pragma("unroll")                                                   \
      for (int nt = 0; nt < 4; ++nt) {                                    \
        bf16x8 bv_ = *(const bf16x8*)&Bl[(bb) + (ks * 4 + nt) * 512 + lane * 8]; \
        acc[nt] = __builtin_amdgcn_mfma_f32_16x16x32_bf16(a[ks], bv_, acc[nt], 0, 0, 0); \
      }                                                                   \
  } while (0)

#define STORE(t)                                                          \
  do {                                                                    \
    float* ob_ = out + ((size_t)(t) * 16) * 64 + l15;                     \
    _Pragma("unroll")                                                     \
    for (int r = 0; r < 4; ++r)                                           \
      _Pragma("unroll")                                                   \
      for (int nt = 0; nt < 4; ++nt)                                      \
        __builtin_nontemporal_store(acc[nt][r], &ob_[(4 * lg + r) * 64 + nt * 16]); \
  } while (0)

  if (bid < 16) {
    // ================= build path: row r = bid*4 + w =================
    int r = bid * 4 + w;
    int c0 = lane * 4;
    float vre0 = (c0 + 0 == r) ? 1.f : 0.f, vim0 = 0.f;
    float vre1 = (c0 + 1 == r) ? 1.f : 0.f, vim1 = 0.f;
    float vre2 = (c0 + 2 == r) ? 1.f : 0.f, vim2 = 0.f;
    float vre3 = (c0 + 3 == r) ? 1.f : 0.f, vim3 = 0.f;

    P8 A, B;
    loadP8(A, 31 * 8, lane, theta, phi);
    for (int it = 0; it < 16; ++it) {
      int bA = 31 - 2 * it;
      int bB = bA - 1;
      loadP8(B, bB * 8, lane, theta, phi);
#pragma unroll
      for (int k = 7; k >= 0; --k)
        layer_step((k & 1) != 0, lane, A.qa[k], A.qb[k], A.cc[k],
                   vre0, vim0, vre1, vim1, vre2, vim2, vre3, vim3);
      if (it < 15)
        loadP8(A, (bB - 1) * 8, lane, theta, phi);
#pragma unroll
      for (int k = 7; k >= 0; --k)
        layer_step((k & 1) != 0, lane, B.qa[k], B.qb[k], B.cc[k],
                   vre0, vim0, vre1, vim1, vre2, vim2, vre3, vim3);
    }

    float oph = outph[r];
    float co = cosf(oph), so = sinf(oph);
    bf16x4 o;
    o[0] = to_bf16(co * vre0 - so * vim0);
    o[1] = to_bf16(co * vre1 - so * vim1);
    o[2] = to_bf16(co * vre2 - so * vim2);
    o[3] = to_bf16(co * vre3 - so * vim3);
    // frag-ordered: 16B B-frag for (row, ks, lg) at r*256 + ks*32 + lg*8
    int ksb = lane >> 3, sub = lane & 7;
    int pos = ksb * 32 + (sub & 3) * 8 + (sub >> 2) * 4;
    *(bf16x4*)(Tb2 + r * 256 + pos) = o;

    __threadfence();          // make Tb2 rows agent-visible
    __syncthreads();          // all 4 waves of this build block done
    if (tid == 0)
      __hip_atomic_fetch_add(flag, 1u, __ATOMIC_RELEASE, __HIP_MEMORY_SCOPE_AGENT);
    // build waves issue their own prefetch now (they skip the pre-spin one)
    ISSUE(La, start);
    ISSUE(Lb, start + 1);
  } else {
    // ============ consumer path: prefetch x under the build ============
    ISSUE(La, start);
    ISSUE(Lb, start + 1);
  }

  // ---- wait until all 16 build blocks have published Tb2 ----
  if (tid == 0) {
    while (__hip_atomic_load(flag, __ATOMIC_ACQUIRE, __HIP_MEMORY_SCOPE_AGENT) != 16u)
      __builtin_amdgcn_s_sleep(32);
  }
  __syncthreads();

  // ---- stage B -> LDS (frag-set idx = ks*4+nt; this wave stages w*8+j) ----
#pragma unroll
  for (int j = 0; j < 8; ++j) {
    int idx = w * 8 + j;
    int ks = idx >> 2, nt = idx & 3;
    const __bf16* src = Tb2 + (nt * 16 + l15) * 256 + ks * 32 + lg * 8;
    GLD_LDS16(src, &Bl[idx * 512]);
  }
  asm volatile("s_waitcnt vmcnt(0)" ::: "memory");
  __syncthreads();            // B ready; no further barriers

  unsigned bb = 0;
  asm volatile("" : "+v"(bb));   // opaque 0: keep B reads in LDS (no LICM/CSE)

  // ---- tile loop (hand-unrolled; static register indexing throughout) ----
  CVT(La);                       // tile start   (loads long since landed)
  if (cnt == 3) {
    MFMA(bb); ISSUE(La, start + 2); STORE(start);
    CVT(Lb);  MFMA(bb); STORE(start + 1);
    CVT(La);  MFMA(bb); STORE(start + 2);
  } else {
    MFMA(bb); STORE(start);
    CVT(Lb);  MFMA(bb); STORE(start + 1);
  }

#undef ISSUE
#undef CVT
#undef MFMA
#undef STORE
}

// ---------------------------------------------------------------------------
extern "C" void kernel_launch(void* const* d_in, const int* in_sizes, int n_in,
                              void* d_out, int out_size, void* d_ws, size_t ws_size,
                              hipStream_t stream) {
  const float* x     = (const float*)d_in[0];
  const float* theta = (const float*)d_in[1];
  const float* phi   = (const float*)d_in[2];
  const float* outph = (const float*)d_in[3];
  float* out = (float*)d_out;

  char* ws = (char*)d_ws;
  unsigned* flag = (unsigned*)ws;                 // 4 B
  __bf16* Tb2    = (__bf16*)(ws + 1024);          // 32 KB frag-ordered T

  (void)hipMemsetAsync(flag, 0, 4, stream);       // async: graph-capture safe
  olk_fused<<<768, 256, 0, stream>>>(x, theta, phi, outph, out, flag, Tb2);
}

// Round 9
// 89.986 us; speedup vs baseline: 18.8308x; 18.8308x over previous
//
#include <hip/hip_runtime.h>
#include <hip/hip_bf16.h>
#include <cstdint>
#include <cstddef>

#define PI_F 3.14159265358979323846f
#define TWO_PI_F 6.28318530717958647692f

typedef __bf16 bf16x8 __attribute__((ext_vector_type(8)));
typedef __bf16 bf16x4 __attribute__((ext_vector_type(4)));
typedef float  f32x4  __attribute__((ext_vector_type(4)));

__device__ __forceinline__ __bf16 to_bf16(float f) { return (__bf16)f; }

// global -> LDS async copy, 16B per lane; LDS dest = wave-uniform base + lane*16
#define GLD_LDS16(gsrc, ldst)                                            \
  __builtin_amdgcn_global_load_lds(                                      \
      (const __attribute__((address_space(1))) void*)(gsrc),             \
      (__attribute__((address_space(3))) void*)(ldst), 16, 0, 0)

// ---------------------------------------------------------------------------
// Kernel P: per-(layer,pair) beamsplitter params -> ws table.
// ---------------------------------------------------------------------------
__global__ __launch_bounds__(256) void olk_params(
    const float* __restrict__ theta, const float* __restrict__ phi,
    float4* __restrict__ t4, float2* __restrict__ t2) {
  int idx = blockIdx.x * 256 + threadIdx.x;  // 256*128 = 32768 total
  float t = fmodf(theta[idx], PI_F);
  float p = phi[idx];
  if (t > 0.5f * PI_F) { t = PI_F - t; p += PI_F; }
  p = fmodf(p, TWO_PI_F);
  float c  = cosf(t), s  = sinf(t);
  float cp = cosf(p), sp = sinf(p);
  t4[idx] = make_float4(cp * c, sp * c, cp * s, sp * s);
  t2[idx] = make_float2(c, s);
}

// ---------------------------------------------------------------------------
// Build kernel: V = e_r^T, then V <- V * T_l for l = 255..0.
// Output written in MFMA fragment order (see olk_mm).
// ---------------------------------------------------------------------------
struct P8 {
  float4 qa[8];
  float4 qb[8];
  float4 cc[8];
};

__device__ __forceinline__ void loadP8(P8& P, int lb, int lane,
    const float4* __restrict__ t4, const float2* __restrict__ t2) {
#pragma unroll
  for (int k = 0; k < 8; ++k) {
    int idx = (lb + k) * 128 + 2 * lane;
    P.qa[k] = t4[idx];
    P.qb[k] = t4[idx + 1];
    P.cc[k] = *(const float4*)&t2[idx];   // idx even -> 16B aligned
  }
}

__device__ __forceinline__ void layer_step(bool odd, int lane,
    float4 qa, float4 qb, float4 cc,
    float& vre0, float& vim0, float& vre1, float& vim1,
    float& vre2, float& vim2, float& vre3, float& vim3) {
  if (!odd) {
    float nr0 = qa.x * vre0 - qa.y * vim0 + qa.z * vre1 - qa.w * vim1;
    float ni0 = qa.x * vim0 + qa.y * vre0 + qa.z * vim1 + qa.w * vre1;
    float nr1 = cc.x * vre1 - cc.y * vre0;
    float ni1 = cc.x * vim1 - cc.y * vim0;
    float nr2 = qb.x * vre2 - qb.y * vim2 + qb.z * vre3 - qb.w * vim3;
    float ni2 = qb.x * vim2 + qb.y * vre2 + qb.z * vim3 + qb.w * vre3;
    float nr3 = cc.z * vre3 - cc.w * vre2;
    float ni3 = cc.z * vim3 - cc.w * vim2;
    vre0 = nr0; vim0 = ni0; vre1 = nr1; vim1 = ni1;
    vre2 = nr2; vim2 = ni2; vre3 = nr3; vim3 = ni3;
  } else {
    int nxt = (lane + 1) & 63, prv = (lane + 63) & 63;
    float xre = __shfl(vre0, nxt, 64);
    float xim = __shfl(vim0, nxt, 64);
    float pre = __shfl(vre3, prv, 64);
    float pim = __shfl(vim3, prv, 64);
    float cp  = __shfl(cc.z, prv, 64);
    float sp  = __shfl(cc.w, prv, 64);
    float nr1 = qa.x * vre1 - qa.y * vim1 + qa.z * vre2 - qa.w * vim2;
    float ni1 = qa.x * vim1 + qa.y * vre1 + qa.z * vim2 + qa.w * vre2;
    float nr2 = cc.x * vre2 - cc.y * vre1;
    float ni2 = cc.x * vim2 - cc.y * vim1;
    float nr3 = qb.x * vre3 - qb.y * vim3 + qb.z * xre - qb.w * xim;
    float ni3 = qb.x * vim3 + qb.y * vre3 + qb.z * xim + qb.w * xre;
    float nr0 = cp * vre0 - sp * pre;
    float ni0 = cp * vim0 - sp * pim;
    vre0 = nr0; vim0 = ni0; vre1 = nr1; vim1 = ni1;
    vre2 = nr2; vim2 = ni2; vre3 = nr3; vim3 = ni3;
  }
}

__global__ __launch_bounds__(256) void olk_build(
    const float* __restrict__ outph,
    const float4* __restrict__ t4, const float2* __restrict__ t2,
    __bf16* __restrict__ Tb2) {
  int lane = threadIdx.x & 63;
  int r = blockIdx.x * 4 + (threadIdx.x >> 6);
  int c0 = lane * 4;
  float vre0 = (c0 + 0 == r) ? 1.f : 0.f, vim0 = 0.f;
  float vre1 = (c0 + 1 == r) ? 1.f : 0.f, vim1 = 0.f;
  float vre2 = (c0 + 2 == r) ? 1.f : 0.f, vim2 = 0.f;
  float vre3 = (c0 + 3 == r) ? 1.f : 0.f, vim3 = 0.f;

  P8 A, B;
  loadP8(A, 31 * 8, lane, t4, t2);
  for (int it = 0; it < 16; ++it) {
    int bA = 31 - 2 * it;
    int bB = bA - 1;
    loadP8(B, bB * 8, lane, t4, t2);
#pragma unroll
    for (int k = 7; k >= 0; --k)
      layer_step((k & 1) != 0, lane, A.qa[k], A.qb[k], A.cc[k],
                 vre0, vim0, vre1, vim1, vre2, vim2, vre3, vim3);
    if (it < 15)
      loadP8(A, (bB - 1) * 8, lane, t4, t2);
#pragma unroll
    for (int k = 7; k >= 0; --k)
      layer_step((k & 1) != 0, lane, B.qa[k], B.qb[k], B.cc[k],
                 vre0, vim0, vre1, vim1, vre2, vim2, vre3, vim3);
  }

  float oph = outph[r];
  float co = cosf(oph), so = sinf(oph);
  bf16x4 o;
  o[0] = to_bf16(co * vre0 - so * vim0);
  o[1] = to_bf16(co * vre1 - so * vim1);
  o[2] = to_bf16(co * vre2 - so * vim2);
  o[3] = to_bf16(co * vre3 - so * vim3);

  // Fragment-ordered store: B-frag (8 bf16) for (row, ks, lg) is contiguous
  // 16B at r*256 + ks*32 + lg*8.
  int ks = lane >> 3, sub = lane & 7;
  int pos = ks * 32 + (sub & 3) * 8 + (sub >> 2) * 4;
  *(bf16x4*)(Tb2 + r * 256 + pos) = o;
}

// ---------------------------------------------------------------------------
// Matmul: out[131072][64] = x[131072][256] @ T[64][256]^T, bf16 MFMA 16x16x32.
// R4 structure (B in LDS staged once; full-N per wave; independent waves, no
// in-loop barriers) with: nontemporal x-loads / out-stores (L3 experiment),
// pinned 16-load bursts, launch_bounds(256,4) with a no-spill budget
// (L 64 + a 16 + acc 16 + misc ~20 < 128), grid 1024 = exactly 4 blocks/CU
// all-resident. Tile-0 burst issues BEFORE the B-stage barrier (latency
// hides under staging); tile-1 burst issues right after CVT(t0) so it
// overlaps MFMA(t0)+STORE(t0).
// ---------------------------------------------------------------------------
__global__ __launch_bounds__(256, 4) void olk_mm(
    const float* __restrict__ x, const __bf16* __restrict__ Tb2,
    float* __restrict__ out) {
  __shared__ __bf16 Bl[32 * 512];   // 32 frag-sets x 64 lanes x 8 bf16 = 32KB
  int tid = threadIdx.x, lane = tid & 63, w = tid >> 6;
  int l15 = lane & 15, lg = lane >> 4;

  int mt0 = (blockIdx.x * 4 + w) * 2;     // this wave's 2 m-tiles

  f32x4 L[16];
  bf16x8 a[8];
  f32x4 acc[4];

#define ISSUE(t)                                                          \
  do {                                                                    \
    const float* xr_ = x + ((size_t)((t) * 16 + l15) << 8) + 4 * lg;      \
    __builtin_amdgcn_sched_barrier(0);                                    \
    _Pragma("unroll")                                                     \
    for (int ks = 0; ks < 8; ++ks) {                                      \
      L[2 * ks]     = __builtin_nontemporal_load((const f32x4*)(xr_ + ks * 32));      \
      L[2 * ks + 1] = __builtin_nontemporal_load((const f32x4*)(xr_ + ks * 32 + 16)); \
    }                                                                     \
    __builtin_amdgcn_sched_barrier(0);                                    \
  } while (0)

#define CVT()                                                             \
  do {                                                                    \
    _Pragma("unroll")                                                     \
    for (int ks = 0; ks < 8; ++ks) {                                      \
      f32x4 lo_ = L[2 * ks], hi_ = L[2 * ks + 1];                         \
      bf16x8 v_;                                                          \
      v_[0] = to_bf16(lo_.x); v_[1] = to_bf16(lo_.y);                     \
      v_[2] = to_bf16(lo_.z); v_[3] = to_bf16(lo_.w);                     \
      v_[4] = to_bf16(hi_.x); v_[5] = to_bf16(hi_.y);                     \
      v_[6] = to_bf16(hi_.z); v_[7] = to_bf16(hi_.w);                     \
      a[ks] = v_;                                                         \
    }                                                                     \
  } while (0)

#define MFMA(bb)                                                          \
  do {                                                                    \
    _Pragma("unroll")                                                     \
    for (int nt = 0; nt < 4; ++nt) acc[nt] = (f32x4){0.f, 0.f, 0.f, 0.f}; \
    _Pragma("unroll")                                                     \
    for (int ks = 0; ks < 8; ++ks)                                        \
      _Pragma("unroll")                                                   \
      for (int nt = 0; nt < 4; ++nt) {                                    \
        bf16x8 bv_ = *(const bf16x8*)&Bl[(bb) + (ks * 4 + nt) * 512 + lane * 8]; \
        acc[nt] = __builtin_amdgcn_mfma_f32_16x16x32_bf16(a[ks], bv_, acc[nt], 0, 0, 0); \
      }                                                                   \
  } while (0)

#define STORE(t)                                                          \
  do {                                                                    \
    float* ob_ = out + ((size_t)(t) * 16) * 64 + l15;                     \
    _Pragma("unroll")                                                     \
    for (int r = 0; r < 4; ++r)                                           \
      _Pragma("unroll")                                                   \
      for (int nt = 0; nt < 4; ++nt)                                      \
        __builtin_nontemporal_store(acc[nt][r], &ob_[(4 * lg + r) * 64 + nt * 16]); \
  } while (0)

  // Tile-0 burst first: its latency hides under B-staging + barrier.
  ISSUE(mt0);

  // Stage B -> LDS (frag-set idx = ks*4+nt; this wave stages w*8+j).
#pragma unroll
  for (int j = 0; j < 8; ++j) {
    int idx = w * 8 + j;
    int ks = idx >> 2, nt = idx & 3;
    const __bf16* src = Tb2 + (nt * 16 + l15) * 256 + ks * 32 + lg * 8;
    GLD_LDS16(src, &Bl[idx * 512]);
  }
  __syncthreads();   // drains vmcnt (B in LDS + tile-0 in regs); one-time

  unsigned bb = 0;
  asm volatile("" : "+v"(bb));   // opaque 0: keep B reads in LDS (no LICM/CSE)

  // ---- tile 0 ----
  CVT();                 // loads already landed (drained at barrier)
  ISSUE(mt0 + 1);        // t1 burst overlaps MFMA(t0)+STORE(t0)
  MFMA(bb);
  STORE(mt0);
  // ---- tile 1 ----
  CVT();
  MFMA(bb);
  STORE(mt0 + 1);

#undef ISSUE
#undef CVT
#undef MFMA
#undef STORE
}

// ---------------------------------------------------------------------------
extern "C" void kernel_launch(void* const* d_in, const int* in_sizes, int n_in,
                              void* d_out, int out_size, void* d_ws, size_t ws_size,
                              hipStream_t stream) {
  const float* x     = (const float*)d_in[0];
  const float* theta = (const float*)d_in[1];
  const float* phi   = (const float*)d_in[2];
  const float* outph = (const float*)d_in[3];
  float* out = (float*)d_out;

  char* ws = (char*)d_ws;
  float4* t4  = (float4*)ws;                      // 512 KB
  float2* t2  = (float2*)(ws + 512 * 1024);       // 256 KB
  __bf16* Tb2 = (__bf16*)(ws + 768 * 1024);       // 32 KB frag-ordered T

  olk_params<<<128, 256, 0, stream>>>(theta, phi, t4, t2);
  olk_build<<<16, 256, 0, stream>>>(outph, t4, t2, Tb2);
  olk_mm<<<1024, 256, 0, stream>>>(x, Tb2, out);
}